// Round 9
// baseline (203.442 us; speedup 1.0000x reference)
//
#include <hip/hip_runtime.h>

#define NGRAPH 4096
#define NNODE  64
#define NDIM   128
#define NFP    2048
#define NLAYER 3
#define GRID   1024  // persistent-ish: 4 blocks/CU x 256 CUs; 4 graphs/block exact
#define PH 136   // sh pitch (bf16): 68 dwords === 4 mod 32 -> bank-uniform b128 row reads
#define PA 72    // sadj pitch: 36 dwords === 4 mod 32 (proven R8 family)

typedef __attribute__((ext_vector_type(8))) short short8;
typedef __attribute__((ext_vector_type(4))) float f32x4;
typedef __bf16 bf16x2 __attribute__((ext_vector_type(2)));

union S8 { short8 s8; unsigned d[4]; };

static __device__ inline ushort f2bf(float f) {  // RNE fp32 -> bf16 (fallback path)
  unsigned u = __float_as_uint(f);
  u += 0x7FFF + ((u >> 16) & 1);
  return (ushort)(u >> 16);
}

// packed fp32x2 -> bf16x2 in one HW instr on gfx950 (v_cvt_pk_bf16_f32)
static __device__ inline unsigned pkbf(float x, float y) {
#if __has_builtin(__builtin_amdgcn_cvt_pk_bf16_f32)
  bf16x2 v = __builtin_amdgcn_cvt_pk_bf16_f32(x, y);
  return __builtin_bit_cast(unsigned, v);
#else
  return (unsigned)f2bf(x) | ((unsigned)f2bf(y) << 16);
#endif
}

// W in bf16, native [l][k_out][d] layout (B-frag reads W rows directly).
__device__ __align__(16) ushort g_wbf[NLAYER * NDIM * NDIM];
// emb in bf16: gather in the hot kernel becomes a pure b128 copy.
__device__ __align__(16) ushort g_ebf[NFP * NDIM];   // 512 KB

__global__ __launch_bounds__(256) void convert_w(const float* __restrict__ W) {
  int i = blockIdx.x * 256 + threadIdx.x;   // 192 blocks, exact
  g_wbf[i] = f2bf(W[i]);
}

__global__ __launch_bounds__(256) void convert_emb(const float* __restrict__ emb) {
  int i = blockIdx.x * 256 + threadIdx.x;   // 1024 blocks, exact
  g_ebf[i] = f2bf(emb[i]);
}

// R17 = R16 body, grid-stride persistent blocks.  R16 post-mortem: occupancy
// stuck at 39% (3 blocks/CU) despite LDS/VGPR permitting 6 -- steady-state
// residency = dispatch-rate x block-lifetime (~49 WG/us x 16us = 3/CU), i.e.
// ramp/dispatch-limited, not resource-limited (R15's slow spill blocks DID
// reach 62% with identical geometry).  Fix: 1024 blocks (4/CU, statically
// resident), each processing exactly 4 graphs (uniform, no tail).  One extra
// barrier per graph protects sh/sadj from the next graph's staging.  Bias
// hoisted out of the graph loop.  Everything else byte-identical to R16:
// single sh + sadj (26.6 KB), 2 barriers/layer, bf16 emb gather, bpermute
// transpose, fbr hoist, W dedup, (256,4) VGPR cap (R10/R15 spill rule).
__global__ __launch_bounds__(256, 4) void mpnn_mfma(
    const int* __restrict__ fps, const float* __restrict__ adj,
    const float* __restrict__ emb, const float* __restrict__ bias,
    float* __restrict__ out) {
  __shared__ __align__(16) ushort sh[NNODE * PH];     // h (in-place)  17408 B
  __shared__ __align__(16) ushort sadj[NNODE * PA];   // adj stage      9216 B

  const int t    = threadIdx.x;
  const int w    = t >> 6;        // wave 0..3
  const int lane = t & 63;
  const int r    = lane & 15;     // MFMA row/col index
  const int q    = lane >> 4;     // quad 0..3
  const int n0   = w << 5;        // wave's 32-wide kout region (m1) == d region (m2)

  // bpermute addresses for the z C-frag -> A-frag quad permute (R8-verified mapping)
  const int addr0 = (r + 32 * (q & 1)) << 2;   // p = 0,1
  const int addr1 = addr0 + 64;                // p = 2,3
  const bool hiQ  = (q >= 2);                  // source register select (node>=16 within 32)

  // ---- bias for all layers, both slabs -> registers (graph-invariant) ----
  float bv[NLAYER][2];
#pragma unroll
  for (int l = 0; l < NLAYER; ++l) {
    bv[l][0] = bias[l * NDIM + n0 + r];
    bv[l][1] = bias[l * NDIM + n0 + 16 + r];
  }

#pragma unroll 1   // real graph loop: no 4x body bloat / cross-graph hoisting
  for (int gi = blockIdx.x; gi < NGRAPH; gi += GRID) {

    // ---- gather h0 = bf16 emb rows -> sh (pure b128 copy, no conversion) ----
    const int* fg = fps + gi * NNODE;
#pragma unroll
    for (int it = 0; it < 4; ++it) {
      int idx = it * 256 + t;               // 1024 b128s
      int n = idx >> 4;
      int c = (idx & 15) << 3;
      short8 v = *(const short8*)(g_ebf + fg[n] * NDIM + c);
      *(short8*)(sh + n * PH + c) = v;
    }

    // ---- adjacency -> sadj: bf16(I + A), cooperatively coalesced ----
    const float* adjg = adj + (size_t)gi * NNODE * NNODE;
#pragma unroll
    for (int it = 0; it < 4; ++it) {
      int idx = it * 256 + t;               // 1024 float4s
      int n = idx >> 4;
      int c = (idx & 15) << 2;
      float4 v = *(const float4*)(adjg + n * NNODE + c);
      v.x += (n == c + 0) ? 1.0f : 0.0f;    // fold residual: I + A
      v.y += (n == c + 1) ? 1.0f : 0.0f;
      v.z += (n == c + 2) ? 1.0f : 0.0f;
      v.w += (n == c + 3) ? 1.0f : 0.0f;
      uint2 u = {pkbf(v.x, v.y), pkbf(v.z, v.w)};
      *(uint2*)(sadj + n * PA + c) = u;
    }

    __syncthreads();   // staging visible (sh: h0, sadj: I+A)

    // ---- (I+A) B-frags -> registers, once per graph (layer-invariant) ----
    // fbr[kh][nt] lane(r,q): (I+A)[node'=nt*16+r][node=kh*32+8q+e]
    short8 fbr[2][4];
#pragma unroll
    for (int kh = 0; kh < 2; ++kh)
#pragma unroll
      for (int nt = 0; nt < 4; ++nt)
        fbr[kh][nt] = *(const short8*)(sadj + (nt * 16 + r) * PA + kh * 32 + 8 * q);

#pragma unroll 1   // real layer loop (R6 lesson)
    for (int l = 0; l < NLAYER; ++l) {
      const ushort* Wl = g_wbf + l * NDIM * NDIM;

      // ---- m1: z[node][n0-region(32)] = relu(h * W^T + b), two 16-slabs ----
      f32x4 acc[2][4];
#pragma unroll
      for (int s = 0; s < 2; ++s)
#pragma unroll
        for (int mt = 0; mt < 4; ++mt)
          acc[s][mt] = (f32x4){bv[l][s], bv[l][s], bv[l][s], bv[l][s]};
#pragma unroll
      for (int k0 = 0; k0 < NDIM; k0 += 32) {
        short8 ah[4];                       // loaded ONCE, feeds both slabs
#pragma unroll
        for (int mt = 0; mt < 4; ++mt)
          ah[mt] = *(const short8*)(sh + (mt * 16 + r) * PH + k0 + 8 * q);
#pragma unroll
        for (int s = 0; s < 2; ++s) {
          short8 bw = *(const short8*)(Wl + (n0 + s * 16 + r) * NDIM + k0 + 8 * q);
#pragma unroll
          for (int mt = 0; mt < 4; ++mt)
            acc[s][mt] = __builtin_amdgcn_mfma_f32_16x16x32_bf16(ah[mt], bw, acc[s][mt], 0, 0, 0);
        }
      }

      // ---- relu -> packed bf16 in registers ----
      unsigned zc[2][4][2];   // [slab][mt: node tile][node pair within quad-rows]
#pragma unroll
      for (int s = 0; s < 2; ++s)
#pragma unroll
        for (int mt = 0; mt < 4; ++mt) {
          f32x4 a = acc[s][mt];
          zc[s][mt][0] = pkbf(fmaxf(a[0], 0.f), fmaxf(a[1], 0.f));
          zc[s][mt][1] = pkbf(fmaxf(a[2], 0.f), fmaxf(a[3], 0.f));
        }

      // ---- m2: houtT[d in n0-region][node'] = zT * (I+A)^T, B-frags from regs ----
      f32x4 acc2[2][4];
#pragma unroll
      for (int s = 0; s < 2; ++s)
#pragma unroll
        for (int nt = 0; nt < 4; ++nt) acc2[s][nt] = (f32x4){0.f, 0.f, 0.f, 0.f};
#pragma unroll
      for (int s = 0; s < 2; ++s) {
#pragma unroll
        for (int kh = 0; kh < 2; ++kh) {
          S8 az;
#pragma unroll
          for (int p = 0; p < 4; ++p) {
            int comp = p & 1;
            int lo = __builtin_amdgcn_ds_bpermute((p < 2) ? addr0 : addr1,
                                                  (int)zc[s][2 * kh][comp]);
            int hi = __builtin_amdgcn_ds_bpermute((p < 2) ? addr0 : addr1,
                                                  (int)zc[s][2 * kh + 1][comp]);
            az.d[p] = (unsigned)(hiQ ? hi : lo);
          }
#pragma unroll
          for (int nt = 0; nt < 4; ++nt)
            acc2[s][nt] = __builtin_amdgcn_mfma_f32_16x16x32_bf16(az.s8, fbr[kh][nt], acc2[s][nt], 0, 0, 0);
        }
      }

      if (l < NLAYER - 1) {
        __syncthreads();   // #1: ALL waves' m1 reads of sh done -> safe to overwrite
#pragma unroll
        for (int s = 0; s < 2; ++s)
#pragma unroll
          for (int nt = 0; nt < 4; ++nt) {
            f32x4 a = acc2[s][nt];
            uint2 u = {pkbf(a[0], a[1]), pkbf(a[2], a[3])};
            *(uint2*)(sh + (nt * 16 + r) * PH + n0 + s * 16 + 4 * q) = u;
          }
        __syncthreads();   // #2: writes visible before next layer's reads
      } else {
        // ---- sum-pool: out[gi][d] = sum_node' h[node'][d] ----
#pragma unroll
        for (int s = 0; s < 2; ++s) {
          f32x4 sum;
#pragma unroll
          for (int i = 0; i < 4; ++i)
            sum[i] = acc2[s][0][i] + acc2[s][1][i] + acc2[s][2][i] + acc2[s][3][i];
#pragma unroll
          for (int m = 1; m <= 8; m <<= 1) {
            sum[0] += __shfl_xor(sum[0], m);
            sum[1] += __shfl_xor(sum[1], m);
            sum[2] += __shfl_xor(sum[2], m);
            sum[3] += __shfl_xor(sum[3], m);
          }
          if (r == 0) {
            float4 o = {sum[0], sum[1], sum[2], sum[3]};
            *(float4*)(out + (size_t)gi * NDIM + n0 + s * 16 + 4 * q) = o;
          }
        }
      }
    }

    __syncthreads();   // last-layer m1 reads of sh done -> next graph may stage
  }
}

extern "C" void kernel_launch(void* const* d_in, const int* in_sizes, int n_in,
                              void* d_out, int out_size, void* d_ws, size_t ws_size,
                              hipStream_t stream) {
  const int*   fps  = (const int*)d_in[0];
  const float* adj  = (const float*)d_in[1];
  const float* emb  = (const float*)d_in[2];
  const float* W    = (const float*)d_in[3];
  const float* bias = (const float*)d_in[4];
  float* out = (float*)d_out;

  hipLaunchKernelGGL(convert_w, dim3(192), dim3(256), 0, stream, W);
  hipLaunchKernelGGL(convert_emb, dim3(1024), dim3(256), 0, stream, emb);
  hipLaunchKernelGGL(mpnn_mfma, dim3(GRID), dim3(256), 0, stream,
                     fps, adj, emb, bias, out);
}

// Round 10
// 166.361 us; speedup vs baseline: 1.2229x; 1.2229x over previous
//
#include <hip/hip_runtime.h>

#define NGRAPH 4096
#define NNODE  64
#define NDIM   128
#define NFP    2048
#define NLAYER 3
#define PH 136   // sh pitch (bf16): 68 dwords === 4 mod 32 -> bank-uniform b128 row reads
#define PA 72    // sadj pitch: 36 dwords === 4 mod 32 (proven R8 family)

typedef __attribute__((ext_vector_type(8))) short short8;
typedef __attribute__((ext_vector_type(4))) float f32x4;
typedef __bf16 bf16x2 __attribute__((ext_vector_type(2)));

union S8 { short8 s8; unsigned d[4]; };

static __device__ inline ushort f2bf(float f) {  // RNE fp32 -> bf16 (fallback path)
  unsigned u = __float_as_uint(f);
  u += 0x7FFF + ((u >> 16) & 1);
  return (ushort)(u >> 16);
}

// packed fp32x2 -> bf16x2 in one HW instr on gfx950 (v_cvt_pk_bf16_f32)
static __device__ inline unsigned pkbf(float x, float y) {
#if __has_builtin(__builtin_amdgcn_cvt_pk_bf16_f32)
  bf16x2 v = __builtin_amdgcn_cvt_pk_bf16_f32(x, y);
  return __builtin_bit_cast(unsigned, v);
#else
  return (unsigned)f2bf(x) | ((unsigned)f2bf(y) << 16);
#endif
}

// W in bf16, native [l][k_out][d] layout (B-frag reads W rows directly).
__device__ __align__(16) ushort g_wbf[NLAYER * NDIM * NDIM];
// emb in bf16: gather in the hot kernel becomes a pure b128 copy.
__device__ __align__(16) ushort g_ebf[NFP * NDIM];   // 512 KB

__global__ __launch_bounds__(256) void convert_w(const float* __restrict__ W) {
  int i = blockIdx.x * 256 + threadIdx.x;   // 192 blocks, exact
  g_wbf[i] = f2bf(W[i]);
}

__global__ __launch_bounds__(256) void convert_emb(const float* __restrict__ emb) {
  int i = blockIdx.x * 256 + threadIdx.x;   // 1024 blocks, exact
  g_ebf[i] = f2bf(emb[i]);
}

// R18: two graphs per 512-thread block, side-by-side.  R17 post-mortem: the
// grid-stride outer loop made the allocator trade spill for occupancy (64
// VGPR + 35 MB scratch writes, and the scratch churn evicted adj from L3:
// +67 MB FETCH).  The durable finding across R8/R16/R17: WG dispatch rate is
// ~46-49 WG/us REGARDLESS of WG size, so waves/CU = rate x waves-per-WG x
// lifetime -> the clean residency lever is more waves per WG.
//   - waves 0-3 -> graph 2*bid, waves 4-7 -> graph 2*bid+1; each 4-wave group
//     runs the byte-identical R16 per-wave code on its own sh/sadj (no outer
//     loop, no loop-carried state -> no new spill surface).
//   - LDS 2 x 26.6 = 53.2 KB -> 3 blocks/CU = 24 waves/CU resource cap; the
//     8-wave WG doubles wave-supply rate so we sit at the resource cap.
//   - block-wide barriers couple the two phase-aligned groups (skew only;
//     R8 ran 8-wave barrier blocks fine).  (512,4): 128-VGPR cap.
__global__ __launch_bounds__(512, 4) void mpnn_mfma(
    const int* __restrict__ fps, const float* __restrict__ adj,
    const float* __restrict__ emb, const float* __restrict__ bias,
    float* __restrict__ out) {
  __shared__ __align__(16) ushort sh[2][NNODE * PH];     // h (in-place)  2x17408 B
  __shared__ __align__(16) ushort sadj[2][NNODE * PA];   // adj stage     2x 9216 B

  const int t    = threadIdx.x;
  const int w    = t >> 6;        // wave 0..7
  const int grp  = w >> 2;        // graph group 0/1
  const int wg   = w & 3;         // wave within group
  const int tg   = t & 255;       // thread within group
  const int lane = t & 63;
  const int r    = lane & 15;     // MFMA row/col index
  const int q    = lane >> 4;     // quad 0..3
  const int n0   = wg << 5;       // wave's 32-wide kout region (m1) == d region (m2)
  const int g    = blockIdx.x * 2 + grp;

  ushort* shg = sh[grp];
  ushort* sag = sadj[grp];

  // bpermute addresses for the z C-frag -> A-frag quad permute (R8-verified
  // mapping).  NOTE: ds_bpermute indexes within the wave (lane = addr>>2), so
  // the mapping is group-independent.
  const int addr0 = (r + 32 * (q & 1)) << 2;   // p = 0,1
  const int addr1 = addr0 + 64;                // p = 2,3
  const bool hiQ  = (q >= 2);                  // source register select (node>=16 within 32)

  // ---- gather h0 = bf16 emb rows -> sh (pure b128 copy, no conversion) ----
  const int* fg = fps + g * NNODE;
#pragma unroll
  for (int it = 0; it < 4; ++it) {
    int idx = it * 256 + tg;              // 1024 b128s per graph
    int n = idx >> 4;
    int c = (idx & 15) << 3;
    short8 v = *(const short8*)(g_ebf + fg[n] * NDIM + c);
    *(short8*)(shg + n * PH + c) = v;
  }

  // ---- adjacency -> sadj: bf16(I + A), cooperatively coalesced per group ----
  const float* adjg = adj + (size_t)g * NNODE * NNODE;
#pragma unroll
  for (int it = 0; it < 4; ++it) {
    int idx = it * 256 + tg;              // 1024 float4s per graph
    int n = idx >> 4;
    int c = (idx & 15) << 2;
    float4 v = *(const float4*)(adjg + n * NNODE + c);
    v.x += (n == c + 0) ? 1.0f : 0.0f;    // fold residual: I + A
    v.y += (n == c + 1) ? 1.0f : 0.0f;
    v.z += (n == c + 2) ? 1.0f : 0.0f;
    v.w += (n == c + 3) ? 1.0f : 0.0f;
    uint2 u = {pkbf(v.x, v.y), pkbf(v.z, v.w)};
    *(uint2*)(sag + n * PA + c) = u;
  }

  // ---- bias for all layers, both slabs -> registers ----
  float bv[NLAYER][2];
#pragma unroll
  for (int l = 0; l < NLAYER; ++l) {
    bv[l][0] = bias[l * NDIM + n0 + r];
    bv[l][1] = bias[l * NDIM + n0 + 16 + r];
  }

  __syncthreads();   // staging visible for both groups

  // ---- (I+A) B-frags -> registers, once per graph (layer-invariant) ----
  // fbr[kh][nt] lane(r,q): (I+A)[node'=nt*16+r][node=kh*32+8q+e]
  short8 fbr[2][4];
#pragma unroll
  for (int kh = 0; kh < 2; ++kh)
#pragma unroll
    for (int nt = 0; nt < 4; ++nt)
      fbr[kh][nt] = *(const short8*)(sag + (nt * 16 + r) * PA + kh * 32 + 8 * q);

#pragma unroll 1   // real layer loop (R6 lesson)
  for (int l = 0; l < NLAYER; ++l) {
    const ushort* Wl = g_wbf + l * NDIM * NDIM;

    // ---- m1: z[node][n0-region(32)] = relu(h * W^T + b), two 16-slabs ----
    f32x4 acc[2][4];
#pragma unroll
    for (int s = 0; s < 2; ++s)
#pragma unroll
      for (int mt = 0; mt < 4; ++mt)
        acc[s][mt] = (f32x4){bv[l][s], bv[l][s], bv[l][s], bv[l][s]};
#pragma unroll
    for (int k0 = 0; k0 < NDIM; k0 += 32) {
      short8 ah[4];                       // loaded ONCE, feeds both slabs
#pragma unroll
      for (int mt = 0; mt < 4; ++mt)
        ah[mt] = *(const short8*)(shg + (mt * 16 + r) * PH + k0 + 8 * q);
#pragma unroll
      for (int s = 0; s < 2; ++s) {
        short8 bw = *(const short8*)(Wl + (n0 + s * 16 + r) * NDIM + k0 + 8 * q);
#pragma unroll
        for (int mt = 0; mt < 4; ++mt)
          acc[s][mt] = __builtin_amdgcn_mfma_f32_16x16x32_bf16(ah[mt], bw, acc[s][mt], 0, 0, 0);
      }
    }

    // ---- relu -> packed bf16 in registers ----
    unsigned zc[2][4][2];   // [slab][mt: node tile][node pair within quad-rows]
#pragma unroll
    for (int s = 0; s < 2; ++s)
#pragma unroll
      for (int mt = 0; mt < 4; ++mt) {
        f32x4 a = acc[s][mt];
        zc[s][mt][0] = pkbf(fmaxf(a[0], 0.f), fmaxf(a[1], 0.f));
        zc[s][mt][1] = pkbf(fmaxf(a[2], 0.f), fmaxf(a[3], 0.f));
      }

    // ---- m2: houtT[d in n0-region][node'] = zT * (I+A)^T, B-frags from regs ----
    f32x4 acc2[2][4];
#pragma unroll
    for (int s = 0; s < 2; ++s)
#pragma unroll
      for (int nt = 0; nt < 4; ++nt) acc2[s][nt] = (f32x4){0.f, 0.f, 0.f, 0.f};
#pragma unroll
    for (int s = 0; s < 2; ++s) {
#pragma unroll
      for (int kh = 0; kh < 2; ++kh) {
        S8 az;
#pragma unroll
        for (int p = 0; p < 4; ++p) {
          int comp = p & 1;
          int lo = __builtin_amdgcn_ds_bpermute((p < 2) ? addr0 : addr1,
                                                (int)zc[s][2 * kh][comp]);
          int hi = __builtin_amdgcn_ds_bpermute((p < 2) ? addr0 : addr1,
                                                (int)zc[s][2 * kh + 1][comp]);
          az.d[p] = (unsigned)(hiQ ? hi : lo);
        }
#pragma unroll
        for (int nt = 0; nt < 4; ++nt)
          acc2[s][nt] = __builtin_amdgcn_mfma_f32_16x16x32_bf16(az.s8, fbr[kh][nt], acc2[s][nt], 0, 0, 0);
      }
    }

    if (l < NLAYER - 1) {
      __syncthreads();   // #1: ALL waves' m1 reads of sh done -> safe to overwrite
#pragma unroll
      for (int s = 0; s < 2; ++s)
#pragma unroll
        for (int nt = 0; nt < 4; ++nt) {
          f32x4 a = acc2[s][nt];
          uint2 u = {pkbf(a[0], a[1]), pkbf(a[2], a[3])};
          *(uint2*)(shg + (nt * 16 + r) * PH + n0 + s * 16 + 4 * q) = u;
        }
      __syncthreads();   // #2: writes visible before next layer's reads
    } else {
      // ---- sum-pool: out[g][d] = sum_node' h[node'][d] ----
#pragma unroll
      for (int s = 0; s < 2; ++s) {
        f32x4 sum;
#pragma unroll
        for (int i = 0; i < 4; ++i)
          sum[i] = acc2[s][0][i] + acc2[s][1][i] + acc2[s][2][i] + acc2[s][3][i];
#pragma unroll
        for (int m = 1; m <= 8; m <<= 1) {
          sum[0] += __shfl_xor(sum[0], m);
          sum[1] += __shfl_xor(sum[1], m);
          sum[2] += __shfl_xor(sum[2], m);
          sum[3] += __shfl_xor(sum[3], m);
        }
        if (r == 0) {
          float4 o = {sum[0], sum[1], sum[2], sum[3]};
          *(float4*)(out + (size_t)g * NDIM + n0 + s * 16 + 4 * q) = o;
        }
      }
    }
  }
}

extern "C" void kernel_launch(void* const* d_in, const int* in_sizes, int n_in,
                              void* d_out, int out_size, void* d_ws, size_t ws_size,
                              hipStream_t stream) {
  const int*   fps  = (const int*)d_in[0];
  const float* adj  = (const float*)d_in[1];
  const float* emb  = (const float*)d_in[2];
  const float* W    = (const float*)d_in[3];
  const float* bias = (const float*)d_in[4];
  float* out = (float*)d_out;

  hipLaunchKernelGGL(convert_w, dim3(192), dim3(256), 0, stream, W);
  hipLaunchKernelGGL(convert_emb, dim3(1024), dim3(256), 0, stream, emb);
  hipLaunchKernelGGL(mpnn_mfma, dim3(NGRAPH / 2), dim3(512), 0, stream,
                     fps, adj, emb, bias, out);
}

// Round 11
// 159.616 us; speedup vs baseline: 1.2746x; 1.0423x over previous
//
#include <hip/hip_runtime.h>

#define NGRAPH 4096
#define NNODE  64
#define NDIM   128
#define NFP    2048
#define NLAYER 3
#define PH 136   // sh pitch (bf16): 68 dwords === 4 mod 32 -> bank-uniform b128 row reads
#define PA 72    // sadj pitch: 36 dwords === 4 mod 32 (proven R8 family)

typedef __attribute__((ext_vector_type(8))) short short8;
typedef __attribute__((ext_vector_type(4))) float f32x4;
typedef __bf16 bf16x2 __attribute__((ext_vector_type(2)));

union S8 { short8 s8; unsigned d[4]; };

static __device__ inline ushort f2bf(float f) {  // RNE fp32 -> bf16 (fallback path)
  unsigned u = __float_as_uint(f);
  u += 0x7FFF + ((u >> 16) & 1);
  return (ushort)(u >> 16);
}

// packed fp32x2 -> bf16x2 in one HW instr on gfx950 (v_cvt_pk_bf16_f32)
static __device__ inline unsigned pkbf(float x, float y) {
#if __has_builtin(__builtin_amdgcn_cvt_pk_bf16_f32)
  bf16x2 v = __builtin_amdgcn_cvt_pk_bf16_f32(x, y);
  return __builtin_bit_cast(unsigned, v);
#else
  return (unsigned)f2bf(x) | ((unsigned)f2bf(y) << 16);
#endif
}

// W in bf16, native [l][k_out][d] layout (B-frag reads W rows directly).
__device__ __align__(16) ushort g_wbf[NLAYER * NDIM * NDIM];
// emb in bf16: gather in the hot kernel becomes a pure b128 copy.
__device__ __align__(16) ushort g_ebf[NFP * NDIM];   // 512 KB

__global__ __launch_bounds__(256) void convert_w(const float* __restrict__ W) {
  int i = blockIdx.x * 256 + threadIdx.x;   // 192 blocks, exact
  g_wbf[i] = f2bf(W[i]);
}

__global__ __launch_bounds__(256) void convert_emb(const float* __restrict__ emb) {
  int i = blockIdx.x * 256 + threadIdx.x;   // 1024 blocks, exact
  g_ebf[i] = f2bf(emb[i]);
}

// R19 = R16 + the z-transpose halved via v_permlane16_swap_b32.
// R13-R18 post-mortems: wall time tracks TOTAL issue-cycles (~750/wave-layer
// x 12 graph-layers/CU-slot ~= 85us), not any single pipe, and occupancy is
// pinned ~12 waves/CU regardless of structure.  The only stream still above
// data-minimum was the transpose: 32 bpermutes + 16 cndmask per wave-layer
// (lo/hi both fetched, half discarded).  Fix: permlane16_swap(X=zc[2kh][c],
// Y=zc[2kh+1][c]) -> X'={X0-15,Y0-15,X32-47,Y32-47}, Y'={X16-31,Y16-31,
// X48-63,Y48-63}; with the single BIJECTIVE addr A = r+32(q&1)+16(q>>1),
// az.d[0..3] = bperm(A, X'c0/X'c1/Y'c0/Y'c1) reproduces the R8-verified
// mapping for all q (derived + checked per-q).  Per wave-layer: bperm 32->16
// (now conflict-free), cndmask 16->0, +8 VALU swaps.  zc clobbered in place:
// no register growth.  Everything else byte-identical to R16.
__global__ __launch_bounds__(256, 4) void mpnn_mfma(
    const int* __restrict__ fps, const float* __restrict__ adj,
    const float* __restrict__ emb, const float* __restrict__ bias,
    float* __restrict__ out) {
  __shared__ __align__(16) ushort sh[NNODE * PH];     // h (in-place)  17408 B
  __shared__ __align__(16) ushort sadj[NNODE * PA];   // adj stage      9216 B

  const int g    = blockIdx.x;
  const int t    = threadIdx.x;
  const int w    = t >> 6;        // wave 0..3
  const int lane = t & 63;
  const int r    = lane & 15;     // MFMA row/col index
  const int q    = lane >> 4;     // quad 0..3
  const int n0   = w << 5;        // wave's 32-wide kout region (m1) == d region (m2)

  // single bijective bpermute address for the permlane-prepped transpose:
  // dest(r,q) pulls lane r + 32*(q&1) + 16*(q>>1)  (byte addr <<2)
  const int addrA = (r + 32 * (q & 1) + 16 * (q >> 1)) << 2;

  // ---- gather h0 = bf16 emb rows -> sh (pure b128 copy, no conversion) ----
  const int* fg = fps + g * NNODE;
#pragma unroll
  for (int it = 0; it < 4; ++it) {
    int idx = it * 256 + t;               // 1024 b128s
    int n = idx >> 4;
    int c = (idx & 15) << 3;
    short8 v = *(const short8*)(g_ebf + fg[n] * NDIM + c);
    *(short8*)(sh + n * PH + c) = v;
  }

  // ---- adjacency -> sadj: bf16(I + A), staged once, cooperatively coalesced ----
  const float* adjg = adj + (size_t)g * NNODE * NNODE;
#pragma unroll
  for (int it = 0; it < 4; ++it) {
    int idx = it * 256 + t;               // 1024 float4s
    int n = idx >> 4;
    int c = (idx & 15) << 2;
    float4 v = *(const float4*)(adjg + n * NNODE + c);
    v.x += (n == c + 0) ? 1.0f : 0.0f;    // fold residual: I + A
    v.y += (n == c + 1) ? 1.0f : 0.0f;
    v.z += (n == c + 2) ? 1.0f : 0.0f;
    v.w += (n == c + 3) ? 1.0f : 0.0f;
    uint2 u = {pkbf(v.x, v.y), pkbf(v.z, v.w)};
    *(uint2*)(sadj + n * PA + c) = u;
  }

  // ---- bias for all layers, both slabs -> registers ----
  float bv[NLAYER][2];
#pragma unroll
  for (int l = 0; l < NLAYER; ++l) {
    bv[l][0] = bias[l * NDIM + n0 + r];
    bv[l][1] = bias[l * NDIM + n0 + 16 + r];
  }

  __syncthreads();   // staging visible (sh: h0, sadj: I+A)

  // ---- (I+A) B-frags -> registers, once per block (layer-invariant) ----
  // fbr[kh][nt] lane(r,q): (I+A)[node'=nt*16+r][node=kh*32+8q+e]
  // sadj is read-only from here on: no barrier needed after the hoist.
  short8 fbr[2][4];
#pragma unroll
  for (int kh = 0; kh < 2; ++kh)
#pragma unroll
    for (int nt = 0; nt < 4; ++nt)
      fbr[kh][nt] = *(const short8*)(sadj + (nt * 16 + r) * PA + kh * 32 + 8 * q);

#pragma unroll 1   // real loop: avoid cross-layer load hoisting -> spill (R6 lesson)
  for (int l = 0; l < NLAYER; ++l) {
    const ushort* Wl = g_wbf + l * NDIM * NDIM;

    // ---- m1: z[node][n0-region(32)] = relu(h * W^T + b), two 16-slabs ----
    f32x4 acc[2][4];
#pragma unroll
    for (int s = 0; s < 2; ++s)
#pragma unroll
      for (int mt = 0; mt < 4; ++mt)
        acc[s][mt] = (f32x4){bv[l][s], bv[l][s], bv[l][s], bv[l][s]};
#pragma unroll
    for (int k0 = 0; k0 < NDIM; k0 += 32) {
      short8 ah[4];                       // loaded ONCE, feeds both slabs
#pragma unroll
      for (int mt = 0; mt < 4; ++mt)
        ah[mt] = *(const short8*)(sh + (mt * 16 + r) * PH + k0 + 8 * q);
#pragma unroll
      for (int s = 0; s < 2; ++s) {
        short8 bw = *(const short8*)(Wl + (n0 + s * 16 + r) * NDIM + k0 + 8 * q);
#pragma unroll
        for (int mt = 0; mt < 4; ++mt)
          acc[s][mt] = __builtin_amdgcn_mfma_f32_16x16x32_bf16(ah[mt], bw, acc[s][mt], 0, 0, 0);
      }
    }

    // ---- relu -> packed bf16 in registers ----
    unsigned zc[2][4][2];   // [slab][mt: node tile][node pair within quad-rows]
#pragma unroll
    for (int s = 0; s < 2; ++s)
#pragma unroll
      for (int mt = 0; mt < 4; ++mt) {
        f32x4 a = acc[s][mt];
        zc[s][mt][0] = pkbf(fmaxf(a[0], 0.f), fmaxf(a[1], 0.f));
        zc[s][mt][1] = pkbf(fmaxf(a[2], 0.f), fmaxf(a[3], 0.f));
      }

    // ---- m2: houtT[d in n0-region][node'] = zT * (I+A)^T ----
    // transpose: permlane16_swap pre-mixes lo/hi mt pairs, then 4 bijective
    // bpermutes assemble the A-frag (16 bperm + 8 swap/wave-layer total).
    f32x4 acc2[2][4];
#pragma unroll
    for (int s = 0; s < 2; ++s)
#pragma unroll
      for (int nt = 0; nt < 4; ++nt) acc2[s][nt] = (f32x4){0.f, 0.f, 0.f, 0.f};
#pragma unroll
    for (int s = 0; s < 2; ++s) {
#pragma unroll
      for (int kh = 0; kh < 2; ++kh) {
        unsigned x0 = zc[s][2 * kh][0], y0 = zc[s][2 * kh + 1][0];
        unsigned x1 = zc[s][2 * kh][1], y1 = zc[s][2 * kh + 1][1];
        // d[16:31]<->s[0:15], d[48:63]<->s[32:47]
        asm("v_permlane16_swap_b32 %0, %1" : "+v"(x0), "+v"(y0));
        asm("v_permlane16_swap_b32 %0, %1" : "+v"(x1), "+v"(y1));
        S8 az;
        az.d[0] = (unsigned)__builtin_amdgcn_ds_bpermute(addrA, (int)x0);
        az.d[1] = (unsigned)__builtin_amdgcn_ds_bpermute(addrA, (int)x1);
        az.d[2] = (unsigned)__builtin_amdgcn_ds_bpermute(addrA, (int)y0);
        az.d[3] = (unsigned)__builtin_amdgcn_ds_bpermute(addrA, (int)y1);
#pragma unroll
        for (int nt = 0; nt < 4; ++nt)
          acc2[s][nt] = __builtin_amdgcn_mfma_f32_16x16x32_bf16(az.s8, fbr[kh][nt], acc2[s][nt], 0, 0, 0);
      }
    }

    if (l < NLAYER - 1) {
      __syncthreads();   // #1: ALL waves' m1 reads of sh done -> safe to overwrite
#pragma unroll
      for (int s = 0; s < 2; ++s)
#pragma unroll
        for (int nt = 0; nt < 4; ++nt) {
          f32x4 a = acc2[s][nt];
          uint2 u = {pkbf(a[0], a[1]), pkbf(a[2], a[3])};
          *(uint2*)(sh + (nt * 16 + r) * PH + n0 + s * 16 + 4 * q) = u;
        }
      __syncthreads();   // #2: writes visible before next layer's reads
    } else {
      // ---- sum-pool: out[g][d] = sum_node' h[node'][d] ----
#pragma unroll
      for (int s = 0; s < 2; ++s) {
        f32x4 sum;
#pragma unroll
        for (int i = 0; i < 4; ++i)
          sum[i] = acc2[s][0][i] + acc2[s][1][i] + acc2[s][2][i] + acc2[s][3][i];
#pragma unroll
        for (int m = 1; m <= 8; m <<= 1) {
          sum[0] += __shfl_xor(sum[0], m);
          sum[1] += __shfl_xor(sum[1], m);
          sum[2] += __shfl_xor(sum[2], m);
          sum[3] += __shfl_xor(sum[3], m);
        }
        if (r == 0) {
          float4 o = {sum[0], sum[1], sum[2], sum[3]};
          *(float4*)(out + (size_t)g * NDIM + n0 + s * 16 + 4 * q) = o;
        }
      }
    }
  }
}

extern "C" void kernel_launch(void* const* d_in, const int* in_sizes, int n_in,
                              void* d_out, int out_size, void* d_ws, size_t ws_size,
                              hipStream_t stream) {
  const int*   fps  = (const int*)d_in[0];
  const float* adj  = (const float*)d_in[1];
  const float* emb  = (const float*)d_in[2];
  const float* W    = (const float*)d_in[3];
  const float* bias = (const float*)d_in[4];
  float* out = (float*)d_out;

  hipLaunchKernelGGL(convert_w, dim3(192), dim3(256), 0, stream, W);
  hipLaunchKernelGGL(convert_emb, dim3(1024), dim3(256), 0, stream, emb);
  hipLaunchKernelGGL(mpnn_mfma, dim3(NGRAPH), dim3(256), 0, stream,
                     fps, adj, emb, bias, out);
}